// Round 9
// baseline (710.600 us; speedup 1.0000x reference)
//
#include <hip/hip_runtime.h>
#include <hip/hip_cooperative_groups.h>

namespace cg = cooperative_groups;

#define N_NODES 50000
#define N_EDGES 600000
#define DIM 128
#define BM 64
#define NT_GEMM ((N_NODES + BM - 1) / BM)     // 782
#define SCAN_CHUNKS ((N_NODES + 255) / 256)   // 196
#define NF4N (N_NODES * DIM / 4)              // 1,600,000
#define W4N (DIM * 2 * DIM / 4)               // 8,192

typedef __attribute__((ext_vector_type(8))) short short8;
typedef __attribute__((ext_vector_type(4))) float f32x4;

struct Args {
  const float4* nf4; const float4* w4; const float* bias;
  const int* src; const int* dst; const float* ew;
  char* nf16; char* w16; char* agg16;
  int* deg; int* cursor; int* gtotal; int* rank; unsigned* srcw;
  float* out;
};

__device__ __forceinline__ unsigned bf16rne(float f) {
  unsigned x = __float_as_uint(f);
  x += 0x7fffu + ((x >> 16) & 1u);
  return x >> 16;
}

__device__ __forceinline__ uint2 pack4(float4 v) {
  uint2 o;
  o.x = bf16rne(v.x) | (bf16rne(v.y) << 16);
  o.y = bf16rne(v.z) | (bf16rne(v.w) << 16);
  return o;
}

__device__ __forceinline__ void fma8(float* a, uint4 v, float w) {
  a[0] += __uint_as_float(v.x << 16) * w;
  a[1] += __uint_as_float(v.x & 0xffff0000u) * w;
  a[2] += __uint_as_float(v.y << 16) * w;
  a[3] += __uint_as_float(v.y & 0xffff0000u) * w;
  a[4] += __uint_as_float(v.z << 16) * w;
  a[5] += __uint_as_float(v.z & 0xffff0000u) * w;
  a[6] += __uint_as_float(v.w << 16) * w;
  a[7] += __uint_as_float(v.w & 0xffff0000u) * w;
}

// ---------------- phase bodies (shared by mega + fallback) ------------------

__device__ __forceinline__ void phase_cvt(const Args& A, int gid, int stride) {
  if (gid == 0) *A.gtotal = 0;
  for (int i = gid; i < N_NODES; i += stride) A.deg[i] = 0;
  for (int i = gid; i < W4N; i += stride)
    reinterpret_cast<uint2*>(A.w16)[i] = pack4(A.w4[i]);
  for (int i = gid; i < NF4N; i += stride)
    reinterpret_cast<uint2*>(A.nf16)[i] = pack4(A.nf4[i]);
}

__device__ __forceinline__ void phase_hist(const Args& A, int gid, int stride) {
  for (int e = gid; e < N_EDGES; e += stride)
    A.rank[e] = atomicAdd(&A.deg[A.dst[e]], 1);
}

__device__ __forceinline__ void phase_scan(const Args& A, int bid, int nblocks, int t) {
  __shared__ int s[256];
  __shared__ int sbase;
  for (int cb = bid; cb < SCAN_CHUNKS; cb += nblocks) {
    int i = cb * 256 + t;
    int v = (i < N_NODES) ? A.deg[i] : 0;
    s[t] = v;
    __syncthreads();
#pragma unroll
    for (int d = 1; d < 256; d <<= 1) {
      int add = (t >= d) ? s[t - d] : 0;
      __syncthreads();
      s[t] += add;
      __syncthreads();
    }
    int incl = s[t];
    if (t == 255) sbase = atomicAdd(A.gtotal, incl);
    __syncthreads();
    if (i < N_NODES) A.cursor[i] = sbase + incl - v;
    __syncthreads();   // protect s/sbase before next chunk
  }
}

__device__ __forceinline__ void phase_scatter(const Args& A, int gid, int stride) {
  for (int e = gid; e < N_EDGES; e += stride) {
    int pos = A.cursor[A.dst[e]] + A.rank[e];
    unsigned wq = (unsigned)rintf(A.ew[e] * 65535.0f);
    A.srcw[pos] = (unsigned)A.src[e] | (wq << 16);
  }
}

__device__ __forceinline__ void phase_gather(const Args& A, int wid, int nwaves, int lane) {
  const int eg = lane >> 3;     // edge group 0..7
  const int c = lane & 7;       // 32B feature chunk 0..7
  const uint4* nfq = (const uint4*)A.nf16;
  uint4* aggq = (uint4*)A.agg16;
  for (int node = wid; node < N_NODES; node += nwaves) {
    int dg = A.deg[node];
    int off = A.cursor[node];
    float a[16];
#pragma unroll
    for (int k = 0; k < 16; ++k) a[k] = 0.f;
    for (int j = eg; j < dg; j += 8) {
      unsigned q = A.srcw[off + j];
      float w = (float)(q >> 16) * (1.0f / 65535.0f);
      const uint4* rp = nfq + (size_t)(q & 0xffffu) * 16 + c * 2;
      uint4 v0 = rp[0];
      uint4 v1 = rp[1];
      fma8(a, v0, w);
      fma8(a + 8, v1, w);
    }
#pragma unroll
    for (int k = 0; k < 16; ++k) {
      a[k] += __shfl_xor(a[k], 8);
      a[k] += __shfl_xor(a[k], 16);
      a[k] += __shfl_xor(a[k], 32);
    }
    if (eg == 0) {
      float inv = 1.0f / (float)max(dg, 1);
      uint4 o0, o1;
      o0.x = bf16rne(a[0] * inv)  | (bf16rne(a[1] * inv) << 16);
      o0.y = bf16rne(a[2] * inv)  | (bf16rne(a[3] * inv) << 16);
      o0.z = bf16rne(a[4] * inv)  | (bf16rne(a[5] * inv) << 16);
      o0.w = bf16rne(a[6] * inv)  | (bf16rne(a[7] * inv) << 16);
      o1.x = bf16rne(a[8] * inv)  | (bf16rne(a[9] * inv) << 16);
      o1.y = bf16rne(a[10] * inv) | (bf16rne(a[11] * inv) << 16);
      o1.z = bf16rne(a[12] * inv) | (bf16rne(a[13] * inv) << 16);
      o1.w = bf16rne(a[14] * inv) | (bf16rne(a[15] * inv) << 16);
      aggq[(size_t)node * 16 + c * 2]     = o0;
      aggq[(size_t)node * 16 + c * 2 + 1] = o1;
    }
  }
}

__device__ __forceinline__ void phase_gemm(const Args& A, int bid, int nblocks, int tid) {
  const int lane = tid & 63;
  const int wv = tid >> 6;              // wave -> output cols wv*32..+32
  const int l16 = lane & 15, lg = lane >> 4;
  for (int tile = bid; tile < NT_GEMM; tile += nblocks) {
    const int node0 = tile * BM;
    f32x4 acc[4][2] = {};
#pragma unroll
    for (int ks = 0; ks < 8; ++ks) {
      const char* abase = (ks < 4) ? A.agg16 : A.nf16;
      const int gbyte = (ks & 3) * 64 + lg * 16;
      short8 a[4], b[2];
#pragma unroll
      for (int m = 0; m < 4; ++m) {
        int node = node0 + m * 16 + l16;
        if (node > N_NODES - 1) node = N_NODES - 1;   // tail: masked at store
        a[m] = *reinterpret_cast<const short8*>(abase + (size_t)node * 256 + gbyte);
      }
#pragma unroll
      for (int n = 0; n < 2; ++n) {
        int r = wv * 32 + n * 16 + l16;
        b[n] = *reinterpret_cast<const short8*>(A.w16 + (size_t)r * 512 + ks * 64 + lg * 16);
      }
#pragma unroll
      for (int m = 0; m < 4; ++m)
#pragma unroll
        for (int n = 0; n < 2; ++n)
          acc[m][n] = __builtin_amdgcn_mfma_f32_16x16x32_bf16(a[m], b[n], acc[m][n], 0, 0, 0);
    }
    // C frag: col = lane&15 (out), row = (lane>>4)*4 + j (node)
#pragma unroll
    for (int m = 0; m < 4; ++m) {
      int row_base = node0 + m * 16 + lg * 4;
#pragma unroll
      for (int n = 0; n < 2; ++n) {
        int o = wv * 32 + n * 16 + l16;
        float bv = A.bias[o];
#pragma unroll
        for (int j = 0; j < 4; ++j) {
          int node = row_base + j;
          if (node < N_NODES) A.out[(size_t)node * DIM + o] = acc[m][n][j] + bv;
        }
      }
    }
  }
}

// ---------------- mega kernel: whole pipeline, one dispatch -----------------
// 6 phases in time; each phase grid-stride at full grid width (round-8 lesson:
// fuse in TIME, not in per-block space). No early returns (grid.sync).
__global__ __launch_bounds__(256, 8) void mega(Args A) {
  cg::grid_group grid = cg::this_grid();
  const int tid = threadIdx.x;
  const int gid = blockIdx.x * 256 + tid;
  const int stride = gridDim.x * 256;

  phase_cvt(A, gid, stride);
  grid.sync();
  phase_hist(A, gid, stride);
  grid.sync();
  phase_scan(A, blockIdx.x, gridDim.x, tid);
  grid.sync();
  phase_scatter(A, gid, stride);
  grid.sync();
  phase_gather(A, gid >> 6, stride >> 6, tid & 63);
  grid.sync();
  phase_gemm(A, blockIdx.x, gridDim.x, tid);
}

// ---------------- fallback kernels (plain dispatches) -----------------------
__global__ __launch_bounds__(256) void k_cvt(Args A) {
  phase_cvt(A, blockIdx.x * 256 + threadIdx.x, gridDim.x * 256);
}
__global__ __launch_bounds__(256) void k_hist(Args A) {
  phase_hist(A, blockIdx.x * 256 + threadIdx.x, gridDim.x * 256);
}
__global__ __launch_bounds__(256) void k_scan(Args A) {
  phase_scan(A, blockIdx.x, gridDim.x, threadIdx.x);
}
__global__ __launch_bounds__(256) void k_scatter(Args A) {
  phase_scatter(A, blockIdx.x * 256 + threadIdx.x, gridDim.x * 256);
}
__global__ __launch_bounds__(256) void k_gather(Args A) {
  int gid = blockIdx.x * 256 + threadIdx.x;
  phase_gather(A, gid >> 6, (gridDim.x * 256) >> 6, threadIdx.x & 63);
}
__global__ __launch_bounds__(256) void k_gemm(Args A) {
  phase_gemm(A, blockIdx.x, gridDim.x, threadIdx.x);
}

extern "C" void kernel_launch(void* const* d_in, const int* in_sizes, int n_in,
                              void* d_out, int out_size, void* d_ws, size_t ws_size,
                              hipStream_t stream) {
  // workspace layout (~30.9 MB of ~256 MiB ws)
  char* ws = (char*)d_ws;
  char* agg16 = ws;                                   // 12,800,000
  char* nf16  = agg16 + (size_t)N_NODES * DIM * 2;    // 12,800,000
  char* w16   = nf16 + (size_t)N_NODES * DIM * 2;     // 65,536
  int*  deg    = (int*)(w16 + DIM * 2 * DIM * 2);     // 200,000
  int*  cursor = deg + N_NODES;                       // 200,000
  int*  gtotal = cursor + N_NODES;                    // 4 (+pad to 1KB)
  int*  rank   = gtotal + 256;                        // 2,400,000
  unsigned* srcw = (unsigned*)(rank + N_EDGES);       // 2,400,000

  Args A;
  A.nf4 = (const float4*)d_in[0];
  A.w4  = (const float4*)d_in[2];
  A.bias = (const float*)d_in[3];
  A.src = (const int*)d_in[4];
  A.dst = (const int*)d_in[5];
  A.ew  = (const float*)d_in[1];
  A.nf16 = nf16; A.w16 = w16; A.agg16 = agg16;
  A.deg = deg; A.cursor = cursor; A.gtotal = gtotal;
  A.rank = rank; A.srcw = srcw;
  A.out = (float*)d_out;

  int nb = 0;
  hipError_t qerr = hipOccupancyMaxActiveBlocksPerMultiprocessor(&nb, mega, 256, 0);
  if (qerr != hipSuccess || nb < 1) nb = 4;
  if (nb > 8) nb = 8;                 // 32 waves/CU cap at 256 thr/block
  int grid = nb * 256;                // 256 CUs on MI355X

  void* kargs[] = {(void*)&A};
  hipError_t err = hipLaunchCooperativeKernel(mega, dim3(grid), dim3(256),
                                              kargs, 0, stream);
  if (err != hipSuccess) {
    // fallback: proven round-6-style multi-dispatch pipeline
    k_cvt<<<(NF4N + 255) / 256, 256, 0, stream>>>(A);
    k_hist<<<(N_EDGES + 255) / 256, 256, 0, stream>>>(A);
    k_scan<<<SCAN_CHUNKS, 256, 0, stream>>>(A);
    k_scatter<<<(N_EDGES + 255) / 256, 256, 0, stream>>>(A);
    k_gather<<<(N_NODES + 3) / 4, 256, 0, stream>>>(A);
    k_gemm<<<NT_GEMM, 256, 0, stream>>>(A);
  }
}

// Round 10
// 445.873 us; speedup vs baseline: 1.5937x; 1.5937x over previous
//
#include <hip/hip_runtime.h>
#include <hip/hip_cooperative_groups.h>

namespace cg = cooperative_groups;

#define N_NODES 50000
#define N_EDGES 600000
#define DIM 128
#define BM 64
#define NT_GEMM ((N_NODES + BM - 1) / BM)     // 782
#define SCAN_CHUNKS ((N_NODES + 255) / 256)   // 196
#define NF4N (N_NODES * DIM / 4)              // 1,600,000
#define W4N (DIM * 2 * DIM / 4)               // 8,192

typedef __attribute__((ext_vector_type(8))) short short8;
typedef __attribute__((ext_vector_type(4))) float f32x4;

struct Args {
  const float4* nf4; const float4* w4; const float* bias;
  const int* src; const int* dst; const float* ew;
  char* nf16; char* w16; char* agg16;
  int* deg; int* cursor; int* gtotal; int* rank; unsigned* srcw;
  float* out;
};

__device__ __forceinline__ unsigned bf16rne(float f) {
  unsigned x = __float_as_uint(f);
  x += 0x7fffu + ((x >> 16) & 1u);
  return x >> 16;
}

__device__ __forceinline__ uint2 pack4(float4 v) {
  uint2 o;
  o.x = bf16rne(v.x) | (bf16rne(v.y) << 16);
  o.y = bf16rne(v.z) | (bf16rne(v.w) << 16);
  return o;
}

__device__ __forceinline__ void fma8(float* a, uint4 v, float w) {
  a[0] += __uint_as_float(v.x << 16) * w;
  a[1] += __uint_as_float(v.x & 0xffff0000u) * w;
  a[2] += __uint_as_float(v.y << 16) * w;
  a[3] += __uint_as_float(v.y & 0xffff0000u) * w;
  a[4] += __uint_as_float(v.z << 16) * w;
  a[5] += __uint_as_float(v.z & 0xffff0000u) * w;
  a[6] += __uint_as_float(v.w << 16) * w;
  a[7] += __uint_as_float(v.w & 0xffff0000u) * w;
}

// ---------------- phase bodies (shared by mega + fallback) ------------------

// P1: gtotal=0, deg=0, W -> bf16  (small)
__device__ __forceinline__ void phase_init(const Args& A, int gid, int stride) {
  if (gid == 0) *A.gtotal = 0;
  for (int i = gid; i < N_NODES; i += stride) A.deg[i] = 0;
  for (int i = gid; i < W4N; i += stride)
    reinterpret_cast<uint2*>(A.w16)[i] = pack4(A.w4[i]);
}

// P2: hist (atomic-latency-bound) co-scheduled with nf->bf16 (BW-bound)
__device__ __forceinline__ void phase_hist_cvt(const Args& A, int gid, int stride) {
  for (int e = gid; e < N_EDGES; e += stride)
    A.rank[e] = atomicAdd(&A.deg[A.dst[e]], 1);
  for (int i = gid; i < NF4N; i += stride)
    reinterpret_cast<uint2*>(A.nf16)[i] = pack4(A.nf4[i]);
}

// P3: exclusive scan of deg -> cursor; block base via atomicAdd (arrival order
// fine: CSR buckets only need disjointness)
__device__ __forceinline__ void phase_scan(const Args& A, int bid, int nblocks, int t) {
  __shared__ int s[256];
  __shared__ int sbase;
  for (int cb = bid; cb < SCAN_CHUNKS; cb += nblocks) {
    int i = cb * 256 + t;
    int v = (i < N_NODES) ? A.deg[i] : 0;
    s[t] = v;
    __syncthreads();
#pragma unroll
    for (int d = 1; d < 256; d <<= 1) {
      int add = (t >= d) ? s[t - d] : 0;
      __syncthreads();
      s[t] += add;
      __syncthreads();
    }
    int incl = s[t];
    if (t == 255) sbase = atomicAdd(A.gtotal, incl);
    __syncthreads();
    if (i < N_NODES) A.cursor[i] = sbase + incl - v;
    __syncthreads();
  }
}

// P4: srcw[cursor[dst]+rank] = src | u16(w*65535)<<16  (no atomics)
__device__ __forceinline__ void phase_scatter(const Args& A, int gid, int stride) {
  for (int e = gid; e < N_EDGES; e += stride) {
    int pos = A.cursor[A.dst[e]] + A.rank[e];
    unsigned wq = (unsigned)rintf(A.ew[e] * 65535.0f);
    A.srcw[pos] = (unsigned)A.src[e] | (wq << 16);
  }
}

// P5: gather — one wave per node iteration; 8 edge-groups x 8 lanes
__device__ __forceinline__ void phase_gather(const Args& A, int wid, int nwaves, int lane) {
  const int eg = lane >> 3;
  const int c = lane & 7;
  const uint4* nfq = (const uint4*)A.nf16;
  uint4* aggq = (uint4*)A.agg16;
  for (int node = wid; node < N_NODES; node += nwaves) {
    int dg = A.deg[node];
    int off = A.cursor[node];
    float a[16];
#pragma unroll
    for (int k = 0; k < 16; ++k) a[k] = 0.f;
    for (int j = eg; j < dg; j += 8) {
      unsigned q = A.srcw[off + j];
      float w = (float)(q >> 16) * (1.0f / 65535.0f);
      const uint4* rp = nfq + (size_t)(q & 0xffffu) * 16 + c * 2;
      uint4 v0 = rp[0];
      uint4 v1 = rp[1];
      fma8(a, v0, w);
      fma8(a + 8, v1, w);
    }
#pragma unroll
    for (int k = 0; k < 16; ++k) {
      a[k] += __shfl_xor(a[k], 8);
      a[k] += __shfl_xor(a[k], 16);
      a[k] += __shfl_xor(a[k], 32);
    }
    if (eg == 0) {
      float inv = 1.0f / (float)max(dg, 1);
      uint4 o0, o1;
      o0.x = bf16rne(a[0] * inv)  | (bf16rne(a[1] * inv) << 16);
      o0.y = bf16rne(a[2] * inv)  | (bf16rne(a[3] * inv) << 16);
      o0.z = bf16rne(a[4] * inv)  | (bf16rne(a[5] * inv) << 16);
      o0.w = bf16rne(a[6] * inv)  | (bf16rne(a[7] * inv) << 16);
      o1.x = bf16rne(a[8] * inv)  | (bf16rne(a[9] * inv) << 16);
      o1.y = bf16rne(a[10] * inv) | (bf16rne(a[11] * inv) << 16);
      o1.z = bf16rne(a[12] * inv) | (bf16rne(a[13] * inv) << 16);
      o1.w = bf16rne(a[14] * inv) | (bf16rne(a[15] * inv) << 16);
      aggq[(size_t)node * 16 + c * 2]     = o0;
      aggq[(size_t)node * 16 + c * 2 + 1] = o1;
    }
  }
}

// P6: MFMA GEMM, BM=64 tiles grid-stride; wave wv -> output cols wv*32..+32
__device__ __forceinline__ void phase_gemm(const Args& A, int bid, int nblocks, int tid) {
  const int lane = tid & 63;
  const int wv = tid >> 6;
  const int l16 = lane & 15, lg = lane >> 4;
  for (int tile = bid; tile < NT_GEMM; tile += nblocks) {
    const int node0 = tile * BM;
    f32x4 acc[4][2] = {};
#pragma unroll
    for (int ks = 0; ks < 8; ++ks) {
      const char* abase = (ks < 4) ? A.agg16 : A.nf16;
      const int gbyte = (ks & 3) * 64 + lg * 16;
      short8 a[4], b[2];
#pragma unroll
      for (int m = 0; m < 4; ++m) {
        int node = node0 + m * 16 + l16;
        if (node > N_NODES - 1) node = N_NODES - 1;   // tail: masked at store
        a[m] = *reinterpret_cast<const short8*>(abase + (size_t)node * 256 + gbyte);
      }
#pragma unroll
      for (int n = 0; n < 2; ++n) {
        int r = wv * 32 + n * 16 + l16;
        b[n] = *reinterpret_cast<const short8*>(A.w16 + (size_t)r * 512 + ks * 64 + lg * 16);
      }
#pragma unroll
      for (int m = 0; m < 4; ++m)
#pragma unroll
        for (int n = 0; n < 2; ++n)
          acc[m][n] = __builtin_amdgcn_mfma_f32_16x16x32_bf16(a[m], b[n], acc[m][n], 0, 0, 0);
    }
#pragma unroll
    for (int m = 0; m < 4; ++m) {
      int row_base = node0 + m * 16 + lg * 4;
#pragma unroll
      for (int n = 0; n < 2; ++n) {
        int o = wv * 32 + n * 16 + l16;
        float bv = A.bias[o];
#pragma unroll
        for (int j = 0; j < 4; ++j) {
          int node = row_base + j;
          if (node < N_NODES) A.out[(size_t)node * DIM + o] = acc[m][n][j] + bv;
        }
      }
    }
  }
}

// ---------------- mega kernel: whole pipeline, one dispatch -----------------
// NOTE: no min-waves clamp (round-9 lesson: __launch_bounds__(256,8) forced a
// 64-VGPR budget -> spill-to-scratch -> 11x slowdown). Compiler allocates
// freely; grid sized from the occupancy query.
__global__ __launch_bounds__(256) void mega(Args A) {
  cg::grid_group grid = cg::this_grid();
  const int tid = threadIdx.x;
  const int gid = blockIdx.x * 256 + tid;
  const int stride = gridDim.x * 256;

  phase_init(A, gid, stride);
  grid.sync();
  phase_hist_cvt(A, gid, stride);
  grid.sync();
  phase_scan(A, blockIdx.x, gridDim.x, tid);
  grid.sync();
  phase_scatter(A, gid, stride);
  grid.sync();
  phase_gather(A, gid >> 6, stride >> 6, tid & 63);
  grid.sync();
  phase_gemm(A, blockIdx.x, gridDim.x, tid);
}

// ---------------- fallback kernels (proven multi-dispatch pipeline) ---------
__global__ __launch_bounds__(256) void k_init(Args A) {
  phase_init(A, blockIdx.x * 256 + threadIdx.x, gridDim.x * 256);
}
__global__ __launch_bounds__(256) void k_hist_cvt(Args A) {
  phase_hist_cvt(A, blockIdx.x * 256 + threadIdx.x, gridDim.x * 256);
}
__global__ __launch_bounds__(256) void k_scan(Args A) {
  phase_scan(A, blockIdx.x, gridDim.x, threadIdx.x);
}
__global__ __launch_bounds__(256) void k_scatter(Args A) {
  phase_scatter(A, blockIdx.x * 256 + threadIdx.x, gridDim.x * 256);
}
__global__ __launch_bounds__(256) void k_gather(Args A) {
  int gid = blockIdx.x * 256 + threadIdx.x;
  phase_gather(A, gid >> 6, (gridDim.x * 256) >> 6, threadIdx.x & 63);
}
__global__ __launch_bounds__(256) void k_gemm(Args A) {
  phase_gemm(A, blockIdx.x, gridDim.x, threadIdx.x);
}

extern "C" void kernel_launch(void* const* d_in, const int* in_sizes, int n_in,
                              void* d_out, int out_size, void* d_ws, size_t ws_size,
                              hipStream_t stream) {
  // workspace layout (~30.9 MB of ~256 MiB ws)
  char* ws = (char*)d_ws;
  char* agg16 = ws;                                   // 12,800,000
  char* nf16  = agg16 + (size_t)N_NODES * DIM * 2;    // 12,800,000
  char* w16   = nf16 + (size_t)N_NODES * DIM * 2;     // 65,536
  int*  deg    = (int*)(w16 + DIM * 2 * DIM * 2);     // 200,000
  int*  cursor = deg + N_NODES;                       // 200,000
  int*  gtotal = cursor + N_NODES;                    // 4 (+pad to 1KB)
  int*  rank   = gtotal + 256;                        // 2,400,000
  unsigned* srcw = (unsigned*)(rank + N_EDGES);       // 2,400,000

  Args A;
  A.nf4 = (const float4*)d_in[0];
  A.w4  = (const float4*)d_in[2];
  A.bias = (const float*)d_in[3];
  A.src = (const int*)d_in[4];
  A.dst = (const int*)d_in[5];
  A.ew  = (const float*)d_in[1];
  A.nf16 = nf16; A.w16 = w16; A.agg16 = agg16;
  A.deg = deg; A.cursor = cursor; A.gtotal = gtotal;
  A.rank = rank; A.srcw = srcw;
  A.out = (float*)d_out;

  int nb = 0;
  hipError_t qerr = hipOccupancyMaxActiveBlocksPerMultiprocessor(&nb, mega, 256, 0);
  bool coop_ok = (qerr == hipSuccess && nb >= 2);
  if (nb > 8) nb = 8;

  hipError_t err = hipErrorUnknown;
  if (coop_ok) {
    int grid = nb * 256;               // 256 CUs on MI355X
    void* kargs[] = {(void*)&A};
    err = hipLaunchCooperativeKernel(mega, dim3(grid), dim3(256), kargs, 0, stream);
  }
  if (err != hipSuccess) {
    // fallback: proven round-6-style multi-dispatch pipeline
    k_init<<<(N_NODES + 255) / 256, 256, 0, stream>>>(A);
    k_hist_cvt<<<(NF4N + 255) / 256, 256, 0, stream>>>(A);
    k_scan<<<SCAN_CHUNKS, 256, 0, stream>>>(A);
    k_scatter<<<(N_EDGES + 255) / 256, 256, 0, stream>>>(A);
    k_gather<<<(N_NODES + 3) / 4, 256, 0, stream>>>(A);
    k_gemm<<<NT_GEMM, 256, 0, stream>>>(A);
  }
}

// Round 11
// 111.857 us; speedup vs baseline: 6.3527x; 3.9861x over previous
//
#include <hip/hip_runtime.h>

#define N_NODES 50000
#define N_EDGES 600000
#define DIM 128
#define BM 128
#define SCAN_BLOCKS ((N_NODES + 255) / 256)   // 196
#define NF4N (N_NODES * DIM / 4)              // 1,600,000
#define W4N (DIM * 2 * DIM / 4)               // 8,192

typedef __attribute__((ext_vector_type(8))) short short8;
typedef __attribute__((ext_vector_type(4))) float f32x4;

__device__ __forceinline__ unsigned bf16rne(float f) {
  unsigned x = __float_as_uint(f);
  x += 0x7fffu + ((x >> 16) & 1u);
  return x >> 16;
}

__device__ __forceinline__ uint2 pack4(float4 v) {
  uint2 o;
  o.x = bf16rne(v.x) | (bf16rne(v.y) << 16);
  o.y = bf16rne(v.z) | (bf16rne(v.w) << 16);
  return o;
}

// ---------------------------------------------------------------------------
// K1: gtotal = 0, deg = 0, W -> bf16   (small; 196 blocks)
// ---------------------------------------------------------------------------
__global__ __launch_bounds__(256) void k_init(
    const float4* __restrict__ w4, uint2* __restrict__ w16d,
    int* __restrict__ deg, int* __restrict__ gtotal) {
  int i = blockIdx.x * 256 + threadIdx.x;
  if (i == 0) *gtotal = 0;
  if (i < N_NODES) deg[i] = 0;
  if (i < W4N) w16d[i] = pack4(w4[i]);
}

// ---------------------------------------------------------------------------
// K2: rank[e] = deg[dst[e]]++   (atomic return -> coalesced store)
// ---------------------------------------------------------------------------
__global__ __launch_bounds__(256) void k_hist(
    const int* __restrict__ dst, int* __restrict__ deg, int* __restrict__ rank) {
  int e = blockIdx.x * 256 + threadIdx.x;
  if (e < N_EDGES) rank[e] = atomicAdd(&deg[dst[e]], 1);
}

// ---------------------------------------------------------------------------
// K3: fused exclusive scan of deg -> cursor; block base via atomicAdd
// (arrival order fine — CSR buckets only need disjointness). Proven r7.
// ---------------------------------------------------------------------------
__global__ __launch_bounds__(256) void k_scan(
    const int* __restrict__ deg, int* __restrict__ cursor,
    int* __restrict__ gtotal) {
  __shared__ int s[256];
  __shared__ int base;
  int t = threadIdx.x;
  int i = blockIdx.x * 256 + t;
  int v = (i < N_NODES) ? deg[i] : 0;
  s[t] = v;
  __syncthreads();
#pragma unroll
  for (int d = 1; d < 256; d <<= 1) {
    int add = (t >= d) ? s[t - d] : 0;
    __syncthreads();
    s[t] += add;
    __syncthreads();
  }
  int incl = s[t];
  if (t == 255) base = atomicAdd(gtotal, incl);
  __syncthreads();
  if (i < N_NODES) cursor[i] = base + incl - v;
}

// ---------------------------------------------------------------------------
// K4: scatter + nf->bf16 conversion (independent loops merged; the random
// 4B scatter writes overlap the BW-bound cvt). Grid = NF4N/256 = 6250.
// ---------------------------------------------------------------------------
__global__ __launch_bounds__(256) void k_scatter_cvt(
    const int* __restrict__ src, const int* __restrict__ dst,
    const float* __restrict__ ew, const int* __restrict__ cursor,
    const int* __restrict__ rank, unsigned* __restrict__ srcw,
    const float4* __restrict__ nf4, uint2* __restrict__ nf16d) {
  int gid = blockIdx.x * 256 + threadIdx.x;
  if (gid < N_EDGES) {
    int pos = cursor[dst[gid]] + rank[gid];
    unsigned wq = (unsigned)rintf(ew[gid] * 65535.0f);
    srcw[pos] = (unsigned)src[gid] | (wq << 16);
  }
  if (gid < NF4N) nf16d[gid] = pack4(nf4[gid]);
}

// ---------------------------------------------------------------------------
// K5: gather (round-6 proven body). wave = 8 groups x 8 lanes; group g takes
// edges j = g, g+8, ...; 8 lanes of a group broadcast-load the same srcw u32;
// lane c loads 32B (2 x uint4) chunk c of the 256B row. Reduce 8/16/32.
// ---------------------------------------------------------------------------
__global__ __launch_bounds__(256) void k_gather(
    const uint4* __restrict__ nfq,   // [N][16] granules of 8 bf16
    const int* __restrict__ cursor, const int* __restrict__ deg,
    const unsigned* __restrict__ srcw, uint4* __restrict__ aggq) {
  int node = blockIdx.x * 4 + (threadIdx.x >> 6);
  int lane = threadIdx.x & 63;
  int g = lane >> 3;          // edge group 0..7
  int c = lane & 7;           // 32B feature chunk 0..7
  int dg = deg[node];
  int off = cursor[node];

  float a[16];
#pragma unroll
  for (int k = 0; k < 16; ++k) a[k] = 0.f;

  for (int j = g; j < dg; j += 8) {
    unsigned q = srcw[off + j];
    float w = (float)(q >> 16) * (1.0f / 65535.0f);
    const uint4* rp = nfq + (size_t)(q & 0xffffu) * 16 + c * 2;
    uint4 v0 = rp[0];
    uint4 v1 = rp[1];
    a[0]  += __uint_as_float(v0.x << 16) * w;
    a[1]  += __uint_as_float(v0.x & 0xffff0000u) * w;
    a[2]  += __uint_as_float(v0.y << 16) * w;
    a[3]  += __uint_as_float(v0.y & 0xffff0000u) * w;
    a[4]  += __uint_as_float(v0.z << 16) * w;
    a[5]  += __uint_as_float(v0.z & 0xffff0000u) * w;
    a[6]  += __uint_as_float(v0.w << 16) * w;
    a[7]  += __uint_as_float(v0.w & 0xffff0000u) * w;
    a[8]  += __uint_as_float(v1.x << 16) * w;
    a[9]  += __uint_as_float(v1.x & 0xffff0000u) * w;
    a[10] += __uint_as_float(v1.y << 16) * w;
    a[11] += __uint_as_float(v1.y & 0xffff0000u) * w;
    a[12] += __uint_as_float(v1.z << 16) * w;
    a[13] += __uint_as_float(v1.z & 0xffff0000u) * w;
    a[14] += __uint_as_float(v1.w << 16) * w;
    a[15] += __uint_as_float(v1.w & 0xffff0000u) * w;
  }
#pragma unroll
  for (int k = 0; k < 16; ++k) {
    a[k] += __shfl_xor(a[k], 8);
    a[k] += __shfl_xor(a[k], 16);
    a[k] += __shfl_xor(a[k], 32);
  }
  if (g == 0) {
    float inv = 1.0f / (float)max(dg, 1);
    uint4 o0, o1;
    o0.x = bf16rne(a[0] * inv)  | (bf16rne(a[1] * inv) << 16);
    o0.y = bf16rne(a[2] * inv)  | (bf16rne(a[3] * inv) << 16);
    o0.z = bf16rne(a[4] * inv)  | (bf16rne(a[5] * inv) << 16);
    o0.w = bf16rne(a[6] * inv)  | (bf16rne(a[7] * inv) << 16);
    o1.x = bf16rne(a[8] * inv)  | (bf16rne(a[9] * inv) << 16);
    o1.y = bf16rne(a[10] * inv) | (bf16rne(a[11] * inv) << 16);
    o1.z = bf16rne(a[12] * inv) | (bf16rne(a[13] * inv) << 16);
    o1.w = bf16rne(a[14] * inv) | (bf16rne(a[15] * inv) << 16);
    aggq[(size_t)node * 16 + c * 2]     = o0;
    aggq[(size_t)node * 16 + c * 2 + 1] = o1;
  }
}

// ---------------------------------------------------------------------------
// K6: out[n,o] = sum_k [h16|nf16][n,k] * W16[o,k] + b[o]  (MFMA, K=256)
// Round-6 proven body: BM=128, 4 waves each a 64x64 quadrant; fragments
// straight from global (W 64KB L2-hot, A rows L3-resident). No LDS.
// ---------------------------------------------------------------------------
__global__ __launch_bounds__(256) void k_gemm(
    const char* __restrict__ h16,   // [N][128] bf16
    const char* __restrict__ nf16,  // [N][128] bf16
    const char* __restrict__ w16,   // [128][256] bf16
    const float* __restrict__ bias,
    float* __restrict__ out) {
  const int tid = threadIdx.x;
  const int node0 = blockIdx.x * BM;
  const int lane = tid & 63;
  const int wv = tid >> 6;
  const int wr = wv >> 1, wc = wv & 1;
  const int l16 = lane & 15, lg = lane >> 4;

  f32x4 acc[4][4] = {};
#pragma unroll
  for (int ks = 0; ks < 8; ++ks) {
    const char* abase = (ks < 4) ? h16 : nf16;
    const int gbyte = (ks & 3) * 64 + lg * 16;
    short8 a[4], b[4];
#pragma unroll
    for (int m = 0; m < 4; ++m) {
      int node = node0 + wr * 64 + m * 16 + l16;
      if (node > N_NODES - 1) node = N_NODES - 1;   // tail: masked at store
      a[m] = *reinterpret_cast<const short8*>(abase + (size_t)node * 256 + gbyte);
    }
#pragma unroll
    for (int n = 0; n < 4; ++n) {
      int r = wc * 64 + n * 16 + l16;
      b[n] = *reinterpret_cast<const short8*>(w16 + (size_t)r * 512 + ks * 64 + lg * 16);
    }
#pragma unroll
    for (int m = 0; m < 4; ++m)
#pragma unroll
      for (int n = 0; n < 4; ++n)
        acc[m][n] = __builtin_amdgcn_mfma_f32_16x16x32_bf16(a[m], b[n], acc[m][n], 0, 0, 0);
  }

  // C frag: col = lane&15 (out), row = (lane>>4)*4 + j (node)
#pragma unroll
  for (int m = 0; m < 4; ++m) {
    int row_base = node0 + wr * 64 + m * 16 + lg * 4;
#pragma unroll
    for (int n = 0; n < 4; ++n) {
      int o = wc * 64 + n * 16 + l16;
      float bv = bias[o];
#pragma unroll
      for (int j = 0; j < 4; ++j) {
        int node = row_base + j;
        if (node < N_NODES) out[(size_t)node * DIM + o] = acc[m][n][j] + bv;
      }
    }
  }
}

extern "C" void kernel_launch(void* const* d_in, const int* in_sizes, int n_in,
                              void* d_out, int out_size, void* d_ws, size_t ws_size,
                              hipStream_t stream) {
  const float* nf  = (const float*)d_in[0];  // [N, 128]
  const float* ew  = (const float*)d_in[1];  // [E, 1]
  const float* W   = (const float*)d_in[2];  // [128, 256]
  const float* b   = (const float*)d_in[3];  // [128]
  const int*   src = (const int*)d_in[4];    // [E]
  const int*   dst = (const int*)d_in[5];    // [E]
  float* out = (float*)d_out;                // [N, 128]

  // workspace layout (~30.9 MB of ~256 MiB ws)
  char* ws = (char*)d_ws;
  char* agg16 = ws;                                   // 12,800,000
  char* nf16  = agg16 + (size_t)N_NODES * DIM * 2;    // 12,800,000
  char* w16   = nf16 + (size_t)N_NODES * DIM * 2;     // 65,536
  int*  deg    = (int*)(w16 + DIM * 2 * DIM * 2);     // 200,000
  int*  cursor = deg + N_NODES;                       // 200,000
  int*  gtotal = cursor + N_NODES;                    // 4 (+pad to 1KB)
  int*  rank   = gtotal + 256;                        // 2,400,000
  unsigned* srcw = (unsigned*)(rank + N_EDGES);       // 2,400,000

  k_init<<<SCAN_BLOCKS, 256, 0, stream>>>(
      (const float4*)W, (uint2*)w16, deg, gtotal);
  k_hist<<<(N_EDGES + 255) / 256, 256, 0, stream>>>(dst, deg, rank);
  k_scan<<<SCAN_BLOCKS, 256, 0, stream>>>(deg, cursor, gtotal);
  k_scatter_cvt<<<NF4N / 256, 256, 0, stream>>>(
      src, dst, ew, cursor, rank, srcw, (const float4*)nf, (uint2*)nf16);
  k_gather<<<N_NODES / 4, 256, 0, stream>>>(
      (const uint4*)nf16, cursor, deg, srcw, (uint4*)agg16);
  k_gemm<<<(N_NODES + BM - 1) / BM, 256, 0, stream>>>(
      agg16, nf16, w16, b, out);
}